// Round 1
// baseline (146.917 us; speedup 1.0000x reference)
//
#include <hip/hip_runtime.h>
#include <math.h>

// ---------------------------------------------------------------------------
// QuantumGenerator: 4 stacked "qcnn" layers over (1024, 4096)-flat tensors.
// Per channel only the top-left 4x4 block of the 8x8 unitary matters
// (psi0[4:8]==0, data=probs[:4]).  BN channel of a layer's output ==
// (input channel >> 2); per-batch flat layout is preserved layer-to-layer.
// ---------------------------------------------------------------------------

#define NB 1024   // blocks for qcnn kernels (x256 threads, x4 grid-stride = 1M patches)

__global__ __launch_bounds__(256) void build_V_kernel(
    const float* __restrict__ w1, const float* __restrict__ w2,
    const float* __restrict__ w3, const float* __restrict__ w4,
    float* __restrict__ V)
{
    int t = blockIdx.x * blockDim.x + threadIdx.x;
    if (t >= 340) return;
    const float* w; float* vout;
    if (t < 256)      { w = w1 + t*18;        vout = V + t*16; }
    else if (t < 320) { w = w2 + (t-256)*18;  vout = V + 4096 + (t-256)*16; }
    else if (t < 336) { w = w3 + (t-320)*18;  vout = V + 5120 + (t-320)*16; }
    else              { w = w4 + (t-336)*18;  vout = V + 5376 + (t-336)*16; }
    // CNOT ring: new[perm[r]] = old[r]
    const int perm[8] = {0,5,7,2,3,6,4,1};
    float U[8][8];
    #pragma unroll
    for (int i=0;i<8;i++)
        #pragma unroll
        for (int j=0;j<8;j++) U[i][j] = (i==j) ? 1.0f : 0.0f;
    for (int l=0;l<6;l++){
        float c0 = cosf(0.5f*w[l*3+0]), s0 = sinf(0.5f*w[l*3+0]);  // qubit 2 (MSB)
        float c1 = cosf(0.5f*w[l*3+1]), s1 = sinf(0.5f*w[l*3+1]);  // qubit 1
        float c2 = cosf(0.5f*w[l*3+2]), s2 = sinf(0.5f*w[l*3+2]);  // qubit 0 (LSB)
        #pragma unroll
        for (int col=0; col<8; col++){
            float v[8];
            #pragma unroll
            for (int r=0;r<8;r++) v[r] = U[r][col];
            // Ry(w2) on bit0
            #pragma unroll
            for (int b=0;b<8;b+=2){ float x=v[b], y=v[b+1]; v[b]=c2*x-s2*y; v[b+1]=s2*x+c2*y; }
            // Ry(w1) on bit1
            #pragma unroll
            for (int g=0;g<8;g+=4)
                #pragma unroll
                for (int i=0;i<2;i++){ int a=g+i, b=g+i+2; float x=v[a], y=v[b]; v[a]=c1*x-s1*y; v[b]=s1*x+c1*y; }
            // Ry(w0) on bit2
            #pragma unroll
            for (int i=0;i<4;i++){ float x=v[i], y=v[i+4]; v[i]=c0*x-s0*y; v[i+4]=s0*x+c0*y; }
            #pragma unroll
            for (int r=0;r<8;r++) U[perm[r]][col] = v[r];
        }
    }
    #pragma unroll
    for (int j=0;j<4;j++)
        #pragma unroll
        for (int k=0;k<4;k++) vout[j*4+k] = U[j][k];
}

// One thread = one (batch, channel, patch).  Total threads = 1024*1024 = 1M
// for every layer (C*P == 1024 always).  NB blocks x 256 threads x 4 iters.
template<int C, int H, int W, bool BN>
__global__ __launch_bounds__(256) void qcnn_kernel(
    const float* __restrict__ x, const float* __restrict__ V,
    const float* __restrict__ scale, const float* __restrict__ shift,
    float* __restrict__ out, float* __restrict__ psum, float* __restrict__ pssq)
{
    constexpr int HW  = H*W;
    constexpr int P   = HW/4;                 // patches per channel: 4,16,64,256
    constexpr int OW  = W/2;
    constexpr int LP  = (P==4)?2:(P==16)?4:(P==64)?6:8;
    constexpr int LOW = (OW==2)?1:(OW==4)?2:(OW==8)?3:4;
    constexpr int OC  = C/4;                  // BN channels of the OUTPUT
    constexpr int CPB = 256/P;                // input channels per block r-range (64,16,4,1)
    constexpr int OCB = (CPB/4) < 1 ? 1 : (CPB/4);  // BN bins per block (16,4,1,1)
    constexpr int DIV = OC/OCB;               // 4,4,4,1
    constexpr int NSLOT = NB/DIV;             // 256,256,256,1024
    constexpr int G   = (4*P < 64) ? 4*P : 64;  // lanes sharing one BN channel

    __shared__ float sBin[2*OCB];
    if (threadIdx.x < 2*OCB) sBin[threadIdx.x] = 0.0f;
    __syncthreads();

    const int r0  = (blockIdx.x & 3) * 256;   // per-batch flat thread range (same all iters)
    const int oc0 = r0 >> (LP+2);

    for (int it=0; it<4; ++it){
        int tid = (it<<18) + (blockIdx.x<<8) + threadIdx.x;   // NB*256 = 2^18
        int b  = tid >> 10;
        int r  = tid & 1023;
        int c  = r >> LP;
        int p  = r & (P-1);
        int oh = p >> LOW;
        int ow = p & (OW-1);
        const float* xb = x + ((size_t)b<<12) + c*HW + (oh*2)*W + (ow*2);
        float2 t0 = *reinterpret_cast<const float2*>(xb);
        float2 t1 = *reinterpret_cast<const float2*>(xb + W);
        float x0=t0.x, x1=t0.y, x2=t1.x, x3=t1.y;
        if constexpr (BN){
            float sc = scale[c], sh = shift[c];
            x0 = fmaxf(x0*sc+sh, 0.0f);
            x1 = fmaxf(x1*sc+sh, 0.0f);
            x2 = fmaxf(x2*sc+sh, 0.0f);
            x3 = fmaxf(x3*sc+sh, 0.0f);
        }
        float nrm = sqrtf(x0*x0 + x1*x1 + x2*x2 + x3*x3);
        float inv = 1.0f / fmaxf(nrm, 1e-9f);
        float a0=x0*inv, a1=x1*inv, a2=x2*inv, a3=x3*inv;
        const float4* Vc = reinterpret_cast<const float4*>(V + c*16);
        float4 v0 = Vc[0], v1 = Vc[1], v2 = Vc[2], v3 = Vc[3];
        float q0 = v0.x*a0 + v0.y*a1 + v0.z*a2 + v0.w*a3;
        float q1 = v1.x*a0 + v1.y*a1 + v1.z*a2 + v1.w*a3;
        float q2 = v2.x*a0 + v2.y*a1 + v2.z*a2 + v2.w*a3;
        float q3 = v3.x*a0 + v3.y*a1 + v3.z*a2 + v3.w*a3;
        q0*=q0; q1*=q1; q2*=q2; q3*=q3;
        float s = q0+q1+q2+q3;
        float dinv = 1.0f / fmaxf(s, 1e-9f);
        float d0=q0*dinv, d1=q1*dinv, d2=q2*dinv, d3=q3*dinv;
        *reinterpret_cast<float4*>(out + ((size_t)b<<12) + c*HW + (p<<2)) =
            make_float4(d0,d1,d2,d3);
        // BN stats of the output (channel = c>>2)
        float ls  = d0+d1+d2+d3;
        float lss = d0*d0 + d1*d1 + d2*d2 + d3*d3;
        #pragma unroll
        for (int off=1; off<G; off<<=1){ ls += __shfl_xor(ls, off); lss += __shfl_xor(lss, off); }
        if ((threadIdx.x & (G-1)) == 0){
            int ocl = (r >> (LP+2)) - oc0;
            atomicAdd(&sBin[ocl], ls);
            atomicAdd(&sBin[OCB + ocl], lss);
        }
    }
    __syncthreads();
    if (threadIdx.x < OCB){
        int slot = blockIdx.x / DIV;
        psum[(oc0 + threadIdx.x)*NSLOT + slot] = sBin[threadIdx.x];
        pssq[(oc0 + threadIdx.x)*NSLOT + slot] = sBin[OCB + threadIdx.x];
    }
}

__global__ __launch_bounds__(256) void stats_kernel(
    const float* __restrict__ psum, const float* __restrict__ pssq,
    const float* __restrict__ gamma, const float* __restrict__ beta,
    float* __restrict__ scale, float* __restrict__ shift,
    int nslot, float invN)
{
    __shared__ float sh[8];
    int oc = blockIdx.x;
    float s=0.0f, ss=0.0f;
    for (int i=threadIdx.x; i<nslot; i+=256){ s += psum[oc*nslot+i]; ss += pssq[oc*nslot+i]; }
    #pragma unroll
    for (int off=32; off; off>>=1){ s += __shfl_down(s, off); ss += __shfl_down(ss, off); }
    int wid = threadIdx.x >> 6, lane = threadIdx.x & 63;
    if (lane==0){ sh[wid]=s; sh[4+wid]=ss; }
    __syncthreads();
    if (threadIdx.x==0){
        s  = sh[0]+sh[1]+sh[2]+sh[3];
        ss = sh[4]+sh[5]+sh[6]+sh[7];
        float mean = s*invN;
        float var  = ss*invN - mean*mean;
        float rinv = 1.0f / sqrtf(var + 1e-5f);
        float sc = gamma[oc]*rinv;
        scale[oc] = sc;
        shift[oc] = beta[oc] - mean*sc;
    }
}

__global__ __launch_bounds__(256) void final_kernel(
    const float* __restrict__ s4, const float* __restrict__ sc_p,
    const float* __restrict__ sh_p, float* __restrict__ out_tanh,
    float* __restrict__ out_bn)
{
    float sc = sc_p[0], sh = sh_p[0];
    int i = blockIdx.x*blockDim.x + threadIdx.x;   // 1M threads over float4s
    float4 v = reinterpret_cast<const float4*>(s4)[i];
    float4 bn = make_float4(v.x*sc+sh, v.y*sc+sh, v.z*sc+sh, v.w*sc+sh);
    reinterpret_cast<float4*>(out_bn)[i] = bn;
    reinterpret_cast<float4*>(out_tanh)[i] =
        make_float4(tanhf(bn.x), tanhf(bn.y), tanhf(bn.z), tanhf(bn.w));
}

extern "C" void kernel_launch(void* const* d_in, const int* in_sizes, int n_in,
                              void* d_out, int out_size, void* d_ws, size_t ws_size,
                              hipStream_t stream)
{
    const float* z      = (const float*)d_in[0];
    const float* w1     = (const float*)d_in[1];
    const float* w2     = (const float*)d_in[2];
    const float* w3     = (const float*)d_in[3];
    const float* w4     = (const float*)d_in[4];
    const float* gamma2 = (const float*)d_in[5];
    const float* beta2  = (const float*)d_in[6];
    const float* gamma3 = (const float*)d_in[7];
    const float* beta3  = (const float*)d_in[8];
    const float* gamma4 = (const float*)d_in[9];
    const float* beta4  = (const float*)d_in[10];
    const float* gammaf = (const float*)d_in[11];
    const float* betaf  = (const float*)d_in[12];
    float* out = (float*)d_out;
    float* ws  = (float*)d_ws;

    // workspace layout (floats)
    float* V      = ws;                 // 5440
    float* scale2 = ws + 5504;  float* shift2 = ws + 5568;
    float* scale3 = ws + 5632;  float* shift3 = ws + 5696;
    float* scale4 = ws + 5760;  float* shift4 = ws + 5824;
    float* scalef = ws + 5888;  float* shiftf = ws + 5952;
    float* ps1 = ws + 6144;   float* pq1 = ws + 22528;   // 64*256 each
    float* ps2 = ws + 38912;  float* pq2 = ws + 43008;   // 16*256
    float* ps3 = ws + 47104;  float* pq3 = ws + 48128;   // 4*256
    float* ps4 = ws + 49152;  float* pq4 = ws + 50176;   // 1*1024
    float* bufA = ws + 65536;                 // 4M floats (s1, then s3)
    float* bufB = ws + 65536 + 4194304;       // 4M floats (s2)
    float* s4   = out + 4194304;              // output slot 1
    float* s4bn = out + 8388608;              // output slot 2

    build_V_kernel<<<2, 256, 0, stream>>>(w1, w2, w3, w4, V);

    // L1: z (1024,256,4,4) -> s1, stats over 64 ch, N=1024*64
    qcnn_kernel<256,4,4,false><<<NB, 256, 0, stream>>>(z, V, nullptr, nullptr, bufA, ps1, pq1);
    stats_kernel<<<64, 256, 0, stream>>>(ps1, pq1, gamma2, beta2, scale2, shift2, 256, 1.0f/65536.0f);

    // L2: relu(bn(s1)) -> s2, stats over 16 ch, N=1024*256
    qcnn_kernel<64,8,8,true><<<NB, 256, 0, stream>>>(bufA, V+4096, scale2, shift2, bufB, ps2, pq2);
    stats_kernel<<<16, 256, 0, stream>>>(ps2, pq2, gamma3, beta3, scale3, shift3, 256, 1.0f/262144.0f);

    // L3: -> s3, stats over 4 ch, N=1024*1024
    qcnn_kernel<16,16,16,true><<<NB, 256, 0, stream>>>(bufB, V+5120, scale3, shift3, bufA, ps3, pq3);
    stats_kernel<<<4, 256, 0, stream>>>(ps3, pq3, gamma4, beta4, scale4, shift4, 256, 1.0f/1048576.0f);

    // L4: -> s4 (written straight to d_out slot 1), stats over 1 ch, N=1024*4096
    qcnn_kernel<4,32,32,true><<<NB, 256, 0, stream>>>(bufA, V+5376, scale4, shift4, s4, ps4, pq4);
    stats_kernel<<<1, 256, 0, stream>>>(ps4, pq4, gammaf, betaf, scalef, shiftf, 1024, 1.0f/4194304.0f);

    // final: s4_bn -> out slot 2, tanh(s4_bn) -> out slot 0
    final_kernel<<<4096, 256, 0, stream>>>(s4, scalef, shiftf, out, s4bn);
}